// Round 4
// baseline (309.847 us; speedup 1.0000x reference)
//
#include <hip/hip_runtime.h>
#include <hip/hip_bf16.h>

// Problem constants
#define NN 20000
#define NGB 625                  // node groups of 32 (2 MFMA subgroups of 16)
#define LOG2E 1.44269504088896f
#define TWOLOG2E 2.88539008177793f

typedef __attribute__((ext_vector_type(8))) short short8;   // 8 bf16 = 4 VGPRs (MFMA A/B frag)
typedef __attribute__((ext_vector_type(4))) float floatx4;  // MFMA C/D frag

__device__ __forceinline__ floatx4 MF(short8 a, short8 b, floatx4 c) {
    return __builtin_amdgcn_mfma_f32_16x16x32_bf16(a, b, c, 0, 0, 0);
}
__device__ __forceinline__ float ex2(float x) { return __builtin_amdgcn_exp2f(x); }
__device__ __forceinline__ float rcp(float x) { return __builtin_amdgcn_rcpf(x); }
__device__ __forceinline__ unsigned short bf16r(float x) {
    return __builtin_bit_cast(unsigned short, __float2bfloat16(x));
}
// barrier that waits ONLY lgkmcnt (LDS) — global prefetch stays in flight.
__device__ __forceinline__ void lds_barrier() {
    asm volatile("s_waitcnt lgkmcnt(0)\n\ts_barrier" ::: "memory");
}
// bank-conflict row swizzle for the h transpose tile (R3-verified, 0 conflicts)
__device__ __forceinline__ int rowswz(int L) {
    return L ^ (((L >> 4) & 1) << 1) ^ ((L >> 3) & 1);
}

// pointwise LSTM cell for 4 rows; writes h into A-frag-major LDS buffer
__device__ __forceinline__ void lstm_cell4(const floatx4* acc, float* cst,
                                           unsigned short* buf, int q, int u) {
    #pragma unroll
    for (int r = 0; r < 4; r++) {
        float gi = acc[0][r], gf = acc[1][r], gg = acc[2][r], go = acc[3][r];
        float ei = ex2(-gi);
        float ef = ex2(-gf);
        float eo = ex2(-go);
        float eg = ex2(-__builtin_fabsf(gg));
        float iG = __builtin_copysignf(1.f - eg, gg) * rcp((1.f + ei) * (1.f + eg));
        float cm = fmaf(cst[r], rcp(1.f + ef), iG);
        cst[r] = cm;
        float ec = ex2(-TWOLOG2E * __builtin_fabsf(cm));
        float h  = __builtin_copysignf(1.f - ec, cm) * rcp((1.f + eo) * (1.f + ec));
        int row = 4*q + r + 16*(u >> 3);
        buf[rowswz(row)*8 + (u & 7)] = bf16r(h);
    }
}

// ---------- prep + sort fused: weight repack (log2e pre-folded), bias sums, padded x, nbr sort ----------
#define PREP_TOT (49152 + 49152 + 12288 + 12288 + 768 + 640000)
__global__ void prep_kernel(const float* __restrict__ x, const int* __restrict__ nbr,
    const float* __restrict__ Wih0, const float* __restrict__ Whh0,
    const float* __restrict__ bih0, const float* __restrict__ bhh0, const float* __restrict__ Wl0,
    const float* __restrict__ Wih1, const float* __restrict__ Whh1,
    const float* __restrict__ bih1, const float* __restrict__ bhh1, const float* __restrict__ Wl1,
    const float* __restrict__ Wih2, const float* __restrict__ Whh2,
    const float* __restrict__ bih2, const float* __restrict__ bhh2, const float* __restrict__ Wl2,
    unsigned short* __restrict__ Wih_p, unsigned short* __restrict__ Whh_p,
    unsigned short* __restrict__ Wlx_p, unsigned short* __restrict__ Wlh_p,
    float* __restrict__ bsum, unsigned short* __restrict__ x32, int* __restrict__ nbrT)
{
    // --- per-node neighbor sort (first 20000 threads) ---
    int tid = blockIdx.x * 256 + threadIdx.x;
    if (tid < NN) {
        int v[32];
        const int4* src = (const int4*)(nbr + tid * 32);
        #pragma unroll
        for (int i = 0; i < 8; i++) {
            int4 t = src[i];
            v[4*i] = t.x; v[4*i+1] = t.y; v[4*i+2] = t.z; v[4*i+3] = t.w;
        }
        #pragma unroll
        for (int k = 2; k <= 32; k <<= 1)
            #pragma unroll
            for (int j = k >> 1; j > 0; j >>= 1)
                #pragma unroll
                for (int i = 0; i < 32; i++) {
                    int ixj = i ^ j;
                    if (ixj > i) {
                        bool up = (i & k) == 0;
                        int a = v[i], b = v[ixj];
                        bool sw = up ? (a > b) : (a < b);
                        if (sw) { v[i] = b; v[ixj] = a; }
                    }
                }
        int g = tid >> 5, m = tid & 31;
        int base = g * 1024 + m;             // nbrT[g][t][m], m in [0,32)
        #pragma unroll
        for (int t = 0; t < 32; t++) nbrT[base + t * 32] = v[t];
    }
    // --- grid-stride repack ---
    for (int i = blockIdx.x * 256 + threadIdx.x; i < PREP_TOT; i += gridDim.x * 256) {
        int j = i;
        if (j < 49152) {                       // Wih_p: [col][k], layer0 K=32 padded from 3
            int l = j >> 14, e = j & 16383;
            if (l == 0) {
                if (e < 8192) {
                    int col = e >> 5, k = e & 31;
                    float sc = (col >= 128 && col < 192) ? TWOLOG2E : LOG2E;
                    float v = (k < 3) ? Wih0[col*3 + k] * sc : 0.f;
                    Wih_p[e] = bf16r(v);
                }
            } else {
                int col = e >> 6, k = e & 63;
                const float* W = (l == 1) ? Wih1 : Wih2;
                float sc = (col >= 128 && col < 192) ? TWOLOG2E : LOG2E;
                Wih_p[l*16384 + e] = bf16r(W[col*64 + k] * sc);
            }
            continue;
        }
        j -= 49152;
        if (j < 49152) {                       // Whh_p
            int l = j >> 14, e = j & 16383;
            int col = e >> 6, k = e & 63;
            const float* W = (l == 0) ? Whh0 : ((l == 1) ? Whh1 : Whh2);
            float sc = (col >= 128 && col < 192) ? TWOLOG2E : LOG2E;
            Whh_p[l*16384 + e] = bf16r(W[col*64 + k] * sc);
            continue;
        }
        j -= 49152;
        if (j < 12288) {                       // Wlx_p, layer0 K=32 padded from 3
            int l = j >> 12, e = j & 4095;
            if (l == 0) {
                if (e < 2048) {
                    int col = e >> 5, k = e & 31;
                    float v = (k < 3) ? Wl0[col*67 + k] : 0.f;
                    Wlx_p[e] = bf16r(v);
                }
            } else {
                int col = e >> 6, k = e & 63;
                const float* W = (l == 1) ? Wl1 : Wl2;
                Wlx_p[l*4096 + e] = bf16r(W[col*128 + k]);
            }
            continue;
        }
        j -= 12288;
        if (j < 12288) {                       // Wlh_p
            int l = j >> 12, e = j & 4095;
            int col = e >> 6, k = e & 63;
            float v = (l == 0) ? Wl0[col*67 + 3 + k]
                               : ((l == 1) ? Wl1 : Wl2)[col*128 + 64 + k];
            Wlh_p[l*4096 + e] = bf16r(v);
            continue;
        }
        j -= 12288;
        if (j < 768) {                         // bsum = (b_ih + b_hh) * scale
            int l = j >> 8, col = j & 255;
            const float* bi = (l == 0) ? bih0 : ((l == 1) ? bih1 : bih2);
            const float* bh = (l == 0) ? bhh0 : ((l == 1) ? bhh1 : bhh2);
            float sc = (col >= 128 && col < 192) ? TWOLOG2E : LOG2E;
            bsum[l*256 + col] = (bi[col] + bh[col]) * sc;
            continue;
        }
        j -= 768;
        {                                      // x32: padded bf16 node features [n][32]
            int n = j >> 5, k = j & 31;
            x32[j] = bf16r((k < 3) ? x[n*3 + k] : 0.f);
        }
    }
}

// ---------- fused LSTM-aggregate + combine (+head), 32 nodes/block ----------
// 4 waves, wave w owns units [16w,16w+16) all 4 gates, for BOTH 16-node subgroups A,B.
// K-step restructured: acc(t+1) = bias + Wih*x(t+1) prefilled in the barrier shadow;
// post-barrier path = ds_read(hA) -> 8 hh-MFMAs -> pointwise. One lgkm-only barrier/step.
template<int XKC, int LASTL>
__global__ __launch_bounds__(256, 3)
void lstm_mfma_kernel(const unsigned short* __restrict__ xsrc,  // bf16 rows, stride XKC*32 shorts
                      const int* __restrict__ nbrT,
                      const unsigned short* __restrict__ Wih,   // bf16 [256][XKC*32]
                      const unsigned short* __restrict__ Whh,   // bf16 [256][64]
                      const float* __restrict__ bsum,           // [256] prescaled
                      const unsigned short* __restrict__ Wlx,   // bf16 [64][XKC*32]
                      const unsigned short* __restrict__ Wlh,   // bf16 [64][64]
                      const float* __restrict__ bl,             // [64]
                      const float* __restrict__ W_out,          // [64] (LASTL only)
                      const float* __restrict__ b_out,          // [1]  (LASTL only)
                      void* __restrict__ hout)                  // bf16[n][64] or float[n] (LASTL)
{
    __shared__ unsigned short sWih[(XKC == 2) ? 256*36 : 16];  // kc=1 frags, stride 36 (pad)
    __shared__ unsigned short sA[2][2][1024];                  // h transpose, dbuf x 2 groups
    __shared__ float sRed[2][4][16];                           // head partials (LASTL)

    const int w    = threadIdx.x >> 6;       // 0..3
    const int lane = threadIdx.x & 63;
    const int q    = lane >> 4;
    const int c    = lane & 15;
    const int XS   = XKC * 32;

    const int g = blockIdx.x;
    const int* nbg = nbrT + g * 1024;

    // stage Wih kc=1 halves into LDS (XKC==2 only)
    if (XKC == 2) {
        for (int i8 = threadIdx.x; i8 < 1024; i8 += 256) {
            int col = i8 >> 2, ko = (i8 & 3) * 8;
            *(short8*)(sWih + col*36 + ko) = *(const short8*)(Wih + col*64 + 32 + ko);
        }
    }

    // persistent fragments: gate tile t4, col = 64*t4 + 16w + c, k = 8q+j (+32 for kc=1)
    short8 fWih0[4];
    short8 fWhh[4][2];
    float  biasv[4];
    #pragma unroll
    for (int t4 = 0; t4 < 4; t4++) {
        int col = 64*t4 + 16*w + c;
        biasv[t4]   = bsum[col];
        fWih0[t4]   = *(const short8*)(Wih + col*XS + q*8);
        fWhh[t4][0] = *(const short8*)(Whh + col*64 + q*8);
        fWhh[t4][1] = *(const short8*)(Whh + col*64 + 32 + q*8);
    }
    __syncthreads();                         // staging + frag loads done (once)

    // prologue: gather x(0), prefill acc(0), gather x(1), idx(2)
    int idxA = nbg[c], idxB = nbg[16 + c];
    short8 xgA[XKC], xgB[XKC];
    #pragma unroll
    for (int kc = 0; kc < XKC; kc++) {
        xgA[kc] = *(const short8*)(xsrc + (long)idxA * XS + kc*32 + q*8);
        xgB[kc] = *(const short8*)(xsrc + (long)idxB * XS + kc*32 + q*8);
    }
    floatx4 accA[4], accB[4];
    #pragma unroll
    for (int t4 = 0; t4 < 4; t4++) {
        floatx4 bb; bb[0] = biasv[t4]; bb[1] = biasv[t4]; bb[2] = biasv[t4]; bb[3] = biasv[t4];
        accA[t4] = MF(xgA[0], fWih0[t4], bb);
        accB[t4] = MF(xgB[0], fWih0[t4], bb);
        if (XKC == 2) {
            short8 wf = *(const short8*)(sWih + (64*t4 + 16*w + c)*36 + q*8);
            accA[t4] = MF(xgA[1], wf, accA[t4]);
            accB[t4] = MF(xgB[1], wf, accB[t4]);
        }
    }
    idxA = nbg[32 + c]; idxB = nbg[48 + c];
    #pragma unroll
    for (int kc = 0; kc < XKC; kc++) {
        xgA[kc] = *(const short8*)(xsrc + (long)idxA * XS + kc*32 + q*8);
        xgB[kc] = *(const short8*)(xsrc + (long)idxB * XS + kc*32 + q*8);
    }
    int idxA2 = nbg[64 + c], idxB2 = nbg[80 + c];

    float cstA[4] = {0.f,0.f,0.f,0.f}, cstB[4] = {0.f,0.f,0.f,0.f};
    short8 hAA[2], hAB[2];
    const int u = 16*w + c;

    #pragma unroll 1
    for (int t = 0; t < 32; t++) {
        if (t > 0) {
            #pragma unroll
            for (int t4 = 0; t4 < 4; t4++) {
                accA[t4] = MF(hAA[0], fWhh[t4][0], accA[t4]);
                accA[t4] = MF(hAA[1], fWhh[t4][1], accA[t4]);
                accB[t4] = MF(hAB[0], fWhh[t4][0], accB[t4]);
                accB[t4] = MF(hAB[1], fWhh[t4][1], accB[t4]);
            }
        }
        unsigned short* bufA = sA[(t+1) & 1][0];
        unsigned short* bufB = sA[(t+1) & 1][1];
        lstm_cell4(accA, cstA, bufA, q, u);
        lstm_cell4(accB, cstB, bufB, q, u);

        if (t < 31) {
            // refill acc with bias + Wih*x(t+1) — executes in the barrier shadow
            #pragma unroll
            for (int t4 = 0; t4 < 4; t4++) {
                floatx4 bb; bb[0] = biasv[t4]; bb[1] = biasv[t4]; bb[2] = biasv[t4]; bb[3] = biasv[t4];
                accA[t4] = MF(xgA[0], fWih0[t4], bb);
                accB[t4] = MF(xgB[0], fWih0[t4], bb);
                if (XKC == 2) {
                    short8 wf = *(const short8*)(sWih + (64*t4 + 16*w + c)*36 + q*8);
                    accA[t4] = MF(xgA[1], wf, accA[t4]);
                    accB[t4] = MF(xgB[1], wf, accB[t4]);
                }
            }
            if (t < 30) {
                #pragma unroll
                for (int kc = 0; kc < XKC; kc++) {
                    xgA[kc] = *(const short8*)(xsrc + (long)idxA2 * XS + kc*32 + q*8);
                    xgB[kc] = *(const short8*)(xsrc + (long)idxB2 * XS + kc*32 + q*8);
                }
                int tn = (t + 3 < 32) ? t + 3 : 31;
                idxA2 = nbg[tn*32 + c];
                idxB2 = nbg[tn*32 + 16 + c];
            }
        }
        lds_barrier();
        const unsigned short* rdA = sA[(t+1) & 1][0];
        const unsigned short* rdB = sA[(t+1) & 1][1];
        hAA[0] = *(const short8*)(rdA + rowswz(lane)*8);
        hAA[1] = *(const short8*)(rdA + 512 + rowswz(lane)*8);
        hAB[0] = *(const short8*)(rdB + rowswz(lane)*8);
        hAB[1] = *(const short8*)(rdB + 512 + rowswz(lane)*8);
    }

    // ---- combine: relu([h_in, agg] @ Wl^T + bl); agg frags = hA (final h) ----
    const int col = 16*w + c;
    short8 fx0 = *(const short8*)(Wlx + col*XS + q*8);
    short8 fx1 = {};
    if (XKC == 2) fx1 = *(const short8*)(Wlx + col*64 + 32 + q*8);
    short8 fh0 = *(const short8*)(Wlh + col*64 + q*8);
    short8 fh1 = *(const short8*)(Wlh + col*64 + 32 + q*8);
    float blv = bl[col];

    short8 hinA[XKC], hinB[XKC];
    #pragma unroll
    for (int kc = 0; kc < XKC; kc++) {
        hinA[kc] = *(const short8*)(xsrc + (long)(32*g + c) * XS + kc*32 + q*8);
        hinB[kc] = *(const short8*)(xsrc + (long)(32*g + 16 + c) * XS + kc*32 + q*8);
    }
    floatx4 aA, aB;
    aA[0] = blv; aA[1] = blv; aA[2] = blv; aA[3] = blv;
    aB = aA;
    aA = MF(hinA[0], fx0, aA);
    aB = MF(hinB[0], fx0, aB);
    if (XKC == 2) { aA = MF(hinA[1], fx1, aA); aB = MF(hinB[1], fx1, aB); }
    aA = MF(hAA[0], fh0, aA); aA = MF(hAA[1], fh1, aA);
    aB = MF(hAB[0], fh0, aB); aB = MF(hAB[1], fh1, aB);

    if (!LASTL) {
        unsigned short* ho = (unsigned short*)hout;
        #pragma unroll
        for (int r = 0; r < 4; r++) {
            ho[(32*g + 4*q + r) * 64 + col]      = bf16r(fmaxf(aA[r], 0.f));
            ho[(32*g + 16 + 4*q + r) * 64 + col] = bf16r(fmaxf(aB[r], 0.f));
        }
    } else {
        float wo = W_out[col];
        float pA[4], pB[4];
        #pragma unroll
        for (int r = 0; r < 4; r++) { pA[r] = fmaxf(aA[r], 0.f) * wo; pB[r] = fmaxf(aB[r], 0.f) * wo; }
        #pragma unroll
        for (int d = 1; d < 16; d <<= 1) {
            #pragma unroll
            for (int r = 0; r < 4; r++) { pA[r] += __shfl_xor(pA[r], d); pB[r] += __shfl_xor(pB[r], d); }
        }
        if (c == 0) {
            #pragma unroll
            for (int r = 0; r < 4; r++) { sRed[0][w][4*q + r] = pA[r]; sRed[1][w][4*q + r] = pB[r]; }
        }
        lds_barrier();
        if (w == 0 && lane < 16) {
            float* outf = (float*)hout;
            float bo = b_out[0];
            outf[32*g + lane]      = sRed[0][0][lane] + sRed[0][1][lane] + sRed[0][2][lane] + sRed[0][3][lane] + bo;
            outf[32*g + 16 + lane] = sRed[1][0][lane] + sRed[1][1][lane] + sRed[1][2][lane] + sRed[1][3][lane] + bo;
        }
    }
}

extern "C" void kernel_launch(void* const* d_in, const int* in_sizes, int n_in,
                              void* d_out, int out_size, void* d_ws, size_t ws_size,
                              hipStream_t stream) {
    (void)in_sizes; (void)n_in; (void)out_size; (void)ws_size;
    const float* node_features = (const float*)d_in[0];
    const int*   nbr           = (const int*)d_in[1];
    const float* Wih[3] = {(const float*)d_in[2],  (const float*)d_in[8],  (const float*)d_in[14]};
    const float* Whh[3] = {(const float*)d_in[3],  (const float*)d_in[9],  (const float*)d_in[15]};
    const float* bih[3] = {(const float*)d_in[4],  (const float*)d_in[10], (const float*)d_in[16]};
    const float* bhh[3] = {(const float*)d_in[5],  (const float*)d_in[11], (const float*)d_in[17]};
    const float* Wl[3]  = {(const float*)d_in[6],  (const float*)d_in[12], (const float*)d_in[18]};
    const float* bl[3]  = {(const float*)d_in[7],  (const float*)d_in[13], (const float*)d_in[19]};
    const float* W_out  = (const float*)d_in[20];
    const float* b_out  = (const float*)d_in[21];

    char* ws = (char*)d_ws;
    int*            nbrT  = (int*)ws;                               // 2,560,000 B
    unsigned short* x32   = (unsigned short*)(ws + 2560000);        // 1,280,000 B
    unsigned short* hb1   = (unsigned short*)(ws + 3840000);        // 2,560,000 B
    unsigned short* hb2   = (unsigned short*)(ws + 6400000);        // 2,560,000 B
    unsigned short* Wih_p = (unsigned short*)(ws + 8960000);        // 98,304 B
    unsigned short* Whh_p = (unsigned short*)(ws + 9058304);        // 98,304 B
    unsigned short* Wlx_p = (unsigned short*)(ws + 9156608);        // 24,576 B
    unsigned short* Wlh_p = (unsigned short*)(ws + 9181184);        // 24,576 B
    float*          bsum  = (float*)(ws + 9205760);                 // 3,072 B

    prep_kernel<<<1024, 256, 0, stream>>>(node_features, nbr,
        Wih[0], Whh[0], bih[0], bhh[0], Wl[0],
        Wih[1], Whh[1], bih[1], bhh[1], Wl[1],
        Wih[2], Whh[2], bih[2], bhh[2], Wl[2],
        Wih_p, Whh_p, Wlx_p, Wlh_p, bsum, x32, nbrT);

    lstm_mfma_kernel<1, 0><<<NGB, 256, 0, stream>>>(x32, nbrT,
        Wih_p,         Whh_p,         bsum,       Wlx_p,        Wlh_p,        bl[0],
        nullptr, nullptr, hb1);
    lstm_mfma_kernel<2, 0><<<NGB, 256, 0, stream>>>(hb1, nbrT,
        Wih_p + 16384, Whh_p + 16384, bsum + 256, Wlx_p + 4096, Wlh_p + 4096, bl[1],
        nullptr, nullptr, hb2);
    lstm_mfma_kernel<2, 1><<<NGB, 256, 0, stream>>>(hb2, nbrT,
        Wih_p + 32768, Whh_p + 32768, bsum + 512, Wlx_p + 8192, Wlh_p + 8192, bl[2],
        W_out, b_out, (float*)d_out);
}